// Round 1
// baseline (771.895 us; speedup 1.0000x reference)
//
#include <hip/hip_runtime.h>

#define B_ 4
#define L_ 1024
#define D_ 1024
#define H_ 16

typedef unsigned short u16;
typedef __attribute__((ext_vector_type(8))) short bf16x8;
typedef __attribute__((ext_vector_type(4))) float f32x4;

__device__ __forceinline__ u16 f2b(float x) {
  union { float f; unsigned u; } v; v.f = x;
  unsigned r = v.u + 0x7FFFu + ((v.u >> 16) & 1u);
  return (u16)(r >> 16);
}

__device__ __forceinline__ void gload_lds16(const void* g, void* lds) {
  __builtin_amdgcn_global_load_lds((const __attribute__((address_space(1))) void*)g,
                                   (__attribute__((address_space(3))) void*)lds, 16, 0, 0);
}

// ---------------- cast query/key/value f32 -> bf16 ----------------
__global__ __launch_bounds__(256) void cast3_kernel(
    const float4* __restrict__ q, const float4* __restrict__ k, const float4* __restrict__ v,
    ushort4* __restrict__ qb, ushort4* __restrict__ kb, ushort4* __restrict__ vb) {
  int idx = blockIdx.x * 256 + threadIdx.x;
  float4 a = q[idx];
  qb[idx] = make_ushort4(f2b(a.x), f2b(a.y), f2b(a.z), f2b(a.w));
  a = k[idx];
  kb[idx] = make_ushort4(f2b(a.x), f2b(a.y), f2b(a.z), f2b(a.w));
  a = v[idx];
  vb[idx] = make_ushort4(f2b(a.x), f2b(a.y), f2b(a.z), f2b(a.w));
}

// ---------------- transpose + cast 6 weights: Wt[n][k] = W[k][n] ----------------
__global__ __launch_bounds__(256) void twt_kernel(
    const float* __restrict__ w0, const float* __restrict__ w1, const float* __restrict__ w2,
    const float* __restrict__ w3, const float* __restrict__ w4, const float* __restrict__ w5,
    u16* __restrict__ t0, u16* __restrict__ t1, u16* __restrict__ t2,
    u16* __restrict__ t3, u16* __restrict__ t4, u16* __restrict__ t5) {
  __shared__ float tile[32][33];
  const float* W; u16* T;
  switch (blockIdx.z) {
    case 0: W = w0; T = t0; break;
    case 1: W = w1; T = t1; break;
    case 2: W = w2; T = t2; break;
    case 3: W = w3; T = t3; break;
    case 4: W = w4; T = t4; break;
    default: W = w5; T = t5; break;
  }
  const int tx = threadIdx.x, ty = threadIdx.y;
  const int n0 = blockIdx.x * 32, k0 = blockIdx.y * 32;
#pragma unroll
  for (int jj = 0; jj < 4; ++jj)
    tile[ty + 8 * jj][tx] = W[(size_t)(k0 + ty + 8 * jj) * D_ + n0 + tx];
  __syncthreads();
#pragma unroll
  for (int jj = 0; jj < 4; ++jj)
    T[(size_t)(n0 + ty + 8 * jj) * D_ + k0 + tx] = f2b(tile[tx][ty + 8 * jj]);
}

// ---------------- chord / bass features -> Kbig segments 1,2 (all batches) ----------------
__global__ __launch_bounds__(256) void chordfeat_kernel(
    const int* __restrict__ pitch, const int* __restrict__ bass,
    const float* __restrict__ Wc, const float* __restrict__ bc,
    const float* __restrict__ Wb, const float* __restrict__ bbias,
    u16* __restrict__ Kbig) {
  const int ll = blockIdx.x, t = threadIdx.x;
  __shared__ float pc[12], bs[12];
  if (t < 12) { pc[t] = (float)pitch[ll * 12 + t]; bs[t] = (float)bass[ll * 12 + t]; }
  __syncthreads();
  for (int n = t; n < D_; n += 256) {
    float c = bc[n], vv = bbias[n];
#pragma unroll
    for (int j = 0; j < 12; ++j) { c += pc[j] * Wc[j * D_ + n]; vv += bs[j] * Wb[j * D_ + n]; }
    const u16 cb = f2b(c), vb2 = f2b(vv);
    const int hh = n >> 6, d = n & 63;
#pragma unroll
    for (int b = 0; b < B_; ++b) {
      const size_t base = ((size_t)((b * H_ + hh) * L_ + ll)) * 192;
      Kbig[base + 64 + d] = cb;
      Kbig[base + 128 + d] = vb2;
    }
  }
}

// ---------------- GEMM: out[m][n] = sum_k A[m][k]*Bt[n][k] + bias[n] ----------------
// M=4096, N=1024, K=1024. MODE 0: scatter bf16 into [b][h][q][192] seg; MODE 1: Vt
// [b][h][d][q] bf16; MODE 2: f32 row-major to d_out.
template<int MODE>
__global__ __launch_bounds__(256) void gemm_bt_kernel(
    const u16* __restrict__ A, const u16* __restrict__ Bt,
    const float* __restrict__ bias, void* __restrict__ dst, int seg) {
  __shared__ u16 lA[128 * 32];
  __shared__ u16 lB[128 * 32];
  const int t = threadIdx.x;
  const int w = t >> 6, l = t & 63;
  const int wm = w >> 1, wn = w & 1;
  const int lr = l & 15, lg = l >> 4;
  const int m0 = blockIdx.y * 128, n0 = blockIdx.x * 128;
  f32x4 acc[4][4];
#pragma unroll
  for (int i = 0; i < 4; ++i)
#pragma unroll
    for (int j = 0; j < 4; ++j)
      acc[i][j] = (f32x4){0.f, 0.f, 0.f, 0.f};

  const int r0 = t >> 2, c0 = t & 3;  // 16B-chunk (row, kchunk) this thread stages

  for (int k0 = 0; k0 < 1024; k0 += 32) {
    gload_lds16(A + (size_t)(m0 + r0) * 1024 + k0 + c0 * 8, &lA[w * 512]);
    gload_lds16(A + (size_t)(m0 + 64 + r0) * 1024 + k0 + c0 * 8, &lA[2048 + w * 512]);
    gload_lds16(Bt + (size_t)(n0 + r0) * 1024 + k0 + c0 * 8, &lB[w * 512]);
    gload_lds16(Bt + (size_t)(n0 + 64 + r0) * 1024 + k0 + c0 * 8, &lB[2048 + w * 512]);
    __syncthreads();
    bf16x8 af[4], bfr[4];
#pragma unroll
    for (int i = 0; i < 4; ++i) {
      af[i]  = *(const bf16x8*)&lA[(wm * 64 + i * 16 + lr) * 32 + lg * 8];
      bfr[i] = *(const bf16x8*)&lB[(wn * 64 + i * 16 + lr) * 32 + lg * 8];
    }
#pragma unroll
    for (int i = 0; i < 4; ++i)
#pragma unroll
      for (int j = 0; j < 4; ++j)
        acc[i][j] = __builtin_amdgcn_mfma_f32_16x16x32_bf16(af[i], bfr[j], acc[i][j], 0, 0, 0);
    __syncthreads();
  }

#pragma unroll
  for (int i = 0; i < 4; ++i) {
    const int mb = m0 + wm * 64 + i * 16 + lg * 4;
#pragma unroll
    for (int j = 0; j < 4; ++j) {
      const int n = n0 + wn * 64 + j * 16 + lr;
      const float bv = bias[n];
#pragma unroll
      for (int r = 0; r < 4; ++r) {
        const int m = mb + r;
        const float val = acc[i][j][r] + bv;
        if (MODE == 0) {
          const int b = m >> 10, qq = m & 1023, hh = n >> 6, d = n & 63;
          ((u16*)dst)[((size_t)((b * H_ + hh) * L_ + qq)) * 192 + seg * 64 + d] = f2b(val);
        } else if (MODE == 1) {
          const int b = m >> 10, qq = m & 1023, hh = n >> 6, d = n & 63;
          ((u16*)dst)[((size_t)((b * H_ + hh) * 64 + d)) * L_ + qq] = f2b(val);
        } else {
          ((float*)dst)[(size_t)m * 1024 + n] = val;
        }
      }
    }
  }
}

// ---------------- attention: scores(192-dim) -> softmax -> attn write -> context ----------------
// block = (b,h,16 q-rows), 256 threads / 4 waves. LDS: 16x1024 f32 score rows (64 KiB).
__global__ __launch_bounds__(256) void attn_kernel(
    const u16* __restrict__ Qbig, const u16* __restrict__ Kbig, const u16* __restrict__ Vt,
    float* __restrict__ attn_out, u16* __restrict__ ctx) {
  __shared__ float sc[16 * 1024];
  const int qt = blockIdx.x, h = blockIdx.y, b = blockIdx.z;
  const int bh = b * H_ + h;
  const int q0 = qt * 16;
  const int t = threadIdx.x, w = t >> 6, l = t & 63;
  const int lr = l & 15, lg = l >> 4;

  // Q fragments for the 6 k-chunks of the 192-dim contraction (held in regs)
  bf16x8 aq[6];
  {
    const u16* Qrow = Qbig + ((size_t)bh * L_ + q0 + lr) * 192 + lg * 8;
#pragma unroll
    for (int c = 0; c < 6; ++c) aq[c] = *(const bf16x8*)(Qrow + c * 32);
  }

  const float scl = 1.0f / 24.0f;  // HD^-0.5 / 3
  // each wave covers kpos [w*256, w*256+256)
  for (int kt = 0; kt < 16; ++kt) {
    const int kp0 = w * 256 + kt * 16;
    const u16* Krow = Kbig + ((size_t)bh * L_ + kp0 + lr) * 192 + lg * 8;
    f32x4 acc = (f32x4){0.f, 0.f, 0.f, 0.f};
#pragma unroll
    for (int c = 0; c < 6; ++c) {
      const bf16x8 bk = *(const bf16x8*)(Krow + c * 32);
      acc = __builtin_amdgcn_mfma_f32_16x16x32_bf16(aq[c], bk, acc, 0, 0, 0);
    }
#pragma unroll
    for (int r = 0; r < 4; ++r)
      sc[(lg * 4 + r) * 1024 + kp0 + lr] = acc[r] * scl;
  }
  __syncthreads();

  // wave-parallel softmax: 16 threads per q-row, each owns 64 strided elements
  {
    const int rr = t >> 4, j = t & 15;
    float sv[64];
#pragma unroll
    for (int i = 0; i < 64; ++i) sv[i] = sc[rr * 1024 + j + i * 16];
    float mx = sv[0];
#pragma unroll
    for (int i = 1; i < 64; ++i) mx = fmaxf(mx, sv[i]);
    mx = fmaxf(mx, __shfl_xor(mx, 1));
    mx = fmaxf(mx, __shfl_xor(mx, 2));
    mx = fmaxf(mx, __shfl_xor(mx, 4));
    mx = fmaxf(mx, __shfl_xor(mx, 8));
    float sum = 0.f;
#pragma unroll
    for (int i = 0; i < 64; ++i) { sv[i] = __expf(sv[i] - mx); sum += sv[i]; }
    sum += __shfl_xor(sum, 1);
    sum += __shfl_xor(sum, 2);
    sum += __shfl_xor(sum, 4);
    sum += __shfl_xor(sum, 8);
    const float inv = 1.0f / sum;
    float* aout = attn_out + ((size_t)bh * L_ + q0 + rr) * L_ + j;
#pragma unroll
    for (int i = 0; i < 64; ++i) {
      const float p = sv[i] * inv;
      sc[rr * 1024 + j + i * 16] = p;
      aout[i * 16] = p;
    }
  }
  __syncthreads();

  // context: each wave owns a 16-wide d-slice, contracts over all 1024 kpos
  {
    const int dw = w * 16;
    const u16* Vrow = Vt + ((size_t)bh * 64 + dw + lr) * L_ + lg * 8;
    f32x4 acc = (f32x4){0.f, 0.f, 0.f, 0.f};
    for (int cc = 0; cc < 32; ++cc) {
      const float* ps = &sc[lr * 1024 + cc * 32 + lg * 8];
      bf16x8 av;
#pragma unroll
      for (int e = 0; e < 8; ++e) av[e] = (short)f2b(ps[e]);
      const bf16x8 bv = *(const bf16x8*)(Vrow + cc * 32);
      acc = __builtin_amdgcn_mfma_f32_16x16x32_bf16(av, bv, acc, 0, 0, 0);
    }
#pragma unroll
    for (int r = 0; r < 4; ++r) {
      const int qq = lg * 4 + r, d = dw + lr;
      ctx[((size_t)(b * L_ + q0 + qq)) * D_ + h * 64 + d] = f2b(acc[r]);
    }
  }
}

extern "C" void kernel_launch(void* const* d_in, const int* in_sizes, int n_in,
                              void* d_out, int out_size, void* d_ws, size_t ws_size,
                              hipStream_t stream) {
  (void)in_sizes; (void)n_in; (void)out_size; (void)ws_size;
  const float* q   = (const float*)d_in[0];
  const float* k   = (const float*)d_in[1];
  const float* v   = (const float*)d_in[2];
  const int* pitch = (const int*)d_in[3];
  const int* bass  = (const int*)d_in[4];
  const float* Wpq = (const float*)d_in[5];  const float* bpq  = (const float*)d_in[6];
  const float* Whq = (const float*)d_in[7];  const float* bhq  = (const float*)d_in[8];
  const float* Wvq = (const float*)d_in[9];  const float* bvq  = (const float*)d_in[10];
  const float* Wk  = (const float*)d_in[11]; const float* bk   = (const float*)d_in[12];
  const float* Wv  = (const float*)d_in[13]; const float* bv   = (const float*)d_in[14];
  const float* Wc  = (const float*)d_in[15]; const float* bc   = (const float*)d_in[16];
  const float* Wb  = (const float*)d_in[17]; const float* bbias= (const float*)d_in[18];
  const float* Wo  = (const float*)d_in[19]; const float* bo   = (const float*)d_in[20];

  char* ws = (char*)d_ws;
  const size_t MB = 1024 * 1024;
  u16* qb   = (u16*)(ws + 0 * MB);   // [4096][1024] bf16
  u16* kb   = (u16*)(ws + 8 * MB);
  u16* vb   = (u16*)(ws + 16 * MB);
  u16* WtPQ = (u16*)(ws + 24 * MB);  // [n][k] bf16
  u16* WtHQ = (u16*)(ws + 26 * MB);
  u16* WtVQ = (u16*)(ws + 28 * MB);
  u16* WtK  = (u16*)(ws + 30 * MB);
  u16* WtV  = (u16*)(ws + 32 * MB);
  u16* WtO  = (u16*)(ws + 34 * MB);
  u16* Qbig = (u16*)(ws + 36 * MB);  // [b][h][q][192] = pq|hq|vq
  u16* Kbig = (u16*)(ws + 60 * MB);  // [b][h][kpos][192] = k|cf|bf
  u16* Vt   = (u16*)(ws + 84 * MB);  // [b][h][d][kpos]
  u16* ctx  = (u16*)(ws + 92 * MB);  // [b*L][D] bf16

  float* out  = (float*)d_out;
  float* attn = out + (size_t)B_ * L_ * D_;

  cast3_kernel<<<dim3(4096), dim3(256), 0, stream>>>(
      (const float4*)q, (const float4*)k, (const float4*)v,
      (ushort4*)qb, (ushort4*)kb, (ushort4*)vb);
  twt_kernel<<<dim3(32, 32, 6), dim3(32, 8), 0, stream>>>(
      Wpq, Whq, Wvq, Wk, Wv, Wo, WtPQ, WtHQ, WtVQ, WtK, WtV, WtO);
  chordfeat_kernel<<<dim3(1024), dim3(256), 0, stream>>>(pitch, bass, Wc, bc, Wb, bbias, Kbig);
  gemm_bt_kernel<0><<<dim3(8, 32), dim3(256), 0, stream>>>(qb, WtPQ, bpq, Qbig, 0);
  gemm_bt_kernel<0><<<dim3(8, 32), dim3(256), 0, stream>>>(qb, WtHQ, bhq, Qbig, 1);
  gemm_bt_kernel<0><<<dim3(8, 32), dim3(256), 0, stream>>>(qb, WtVQ, bvq, Qbig, 2);
  gemm_bt_kernel<0><<<dim3(8, 32), dim3(256), 0, stream>>>(kb, WtK, bk, Kbig, 0);
  gemm_bt_kernel<1><<<dim3(8, 32), dim3(256), 0, stream>>>(vb, WtV, bv, Vt, 0);
  attn_kernel<<<dim3(64, 16, 4), dim3(256), 0, stream>>>(Qbig, Kbig, Vt, attn, ctx);
  gemm_bt_kernel<2><<<dim3(8, 32), dim3(256), 0, stream>>>(ctx, WtO, bo, out, 0);
}

// Round 7
// 731.764 us; speedup vs baseline: 1.0548x; 1.0548x over previous
//
#include <hip/hip_runtime.h>

#define B_ 4
#define L_ 1024
#define D_ 1024
#define H_ 16

typedef unsigned short u16;
typedef __attribute__((ext_vector_type(8))) short bf16x8;
typedef __attribute__((ext_vector_type(4))) float f32x4;

__device__ __forceinline__ u16 f2b(float x) {
  union { float f; unsigned u; } v; v.f = x;
  unsigned r = v.u + 0x7FFFu + ((v.u >> 16) & 1u);
  return (u16)(r >> 16);
}

__device__ __forceinline__ void gload_lds16(const void* g, void* lds) {
  __builtin_amdgcn_global_load_lds((const __attribute__((address_space(1))) void*)g,
                                   (__attribute__((address_space(3))) void*)lds, 16, 0, 0);
}

// ---------------- cast query/key/value f32 -> bf16 ----------------
__global__ __launch_bounds__(256) void cast3_kernel(
    const float4* __restrict__ q, const float4* __restrict__ k, const float4* __restrict__ v,
    ushort4* __restrict__ qb, ushort4* __restrict__ kb, ushort4* __restrict__ vb) {
  int idx = blockIdx.x * 256 + threadIdx.x;
  float4 a = q[idx];
  qb[idx] = make_ushort4(f2b(a.x), f2b(a.y), f2b(a.z), f2b(a.w));
  a = k[idx];
  kb[idx] = make_ushort4(f2b(a.x), f2b(a.y), f2b(a.z), f2b(a.w));
  a = v[idx];
  vb[idx] = make_ushort4(f2b(a.x), f2b(a.y), f2b(a.z), f2b(a.w));
}

// ---------------- transpose + cast 6 weights: Wt[n][k] = W[k][n] ----------------
__global__ __launch_bounds__(256) void twt_kernel(
    const float* __restrict__ w0, const float* __restrict__ w1, const float* __restrict__ w2,
    const float* __restrict__ w3, const float* __restrict__ w4, const float* __restrict__ w5,
    u16* __restrict__ t0, u16* __restrict__ t1, u16* __restrict__ t2,
    u16* __restrict__ t3, u16* __restrict__ t4, u16* __restrict__ t5) {
  __shared__ float tile[32][33];
  const float* W; u16* T;
  switch (blockIdx.z) {
    case 0: W = w0; T = t0; break;
    case 1: W = w1; T = t1; break;
    case 2: W = w2; T = t2; break;
    case 3: W = w3; T = t3; break;
    case 4: W = w4; T = t4; break;
    default: W = w5; T = t5; break;
  }
  const int tx = threadIdx.x, ty = threadIdx.y;
  const int n0 = blockIdx.x * 32, k0 = blockIdx.y * 32;
#pragma unroll
  for (int jj = 0; jj < 4; ++jj)
    tile[ty + 8 * jj][tx] = W[(size_t)(k0 + ty + 8 * jj) * D_ + n0 + tx];
  __syncthreads();
#pragma unroll
  for (int jj = 0; jj < 4; ++jj)
    T[(size_t)(n0 + ty + 8 * jj) * D_ + k0 + tx] = f2b(tile[tx][ty + 8 * jj]);
}

// ---------------- chord / bass features -> Kbig segments 1,2 (all batches) ----------------
__global__ __launch_bounds__(256) void chordfeat_kernel(
    const int* __restrict__ pitch, const int* __restrict__ bass,
    const float* __restrict__ Wc, const float* __restrict__ bc,
    const float* __restrict__ Wb, const float* __restrict__ bbias,
    u16* __restrict__ Kbig) {
  const int ll = blockIdx.x, t = threadIdx.x;
  __shared__ float pc[12], bs[12];
  if (t < 12) { pc[t] = (float)pitch[ll * 12 + t]; bs[t] = (float)bass[ll * 12 + t]; }
  __syncthreads();
  for (int n = t; n < D_; n += 256) {
    float c = bc[n], vv = bbias[n];
#pragma unroll
    for (int j = 0; j < 12; ++j) { c += pc[j] * Wc[j * D_ + n]; vv += bs[j] * Wb[j * D_ + n]; }
    const u16 cb = f2b(c), vb2 = f2b(vv);
    const int hh = n >> 6, d = n & 63;
#pragma unroll
    for (int b = 0; b < B_; ++b) {
      const size_t base = ((size_t)((b * H_ + hh) * L_ + ll)) * 192;
      Kbig[base + 64 + d] = cb;
      Kbig[base + 128 + d] = vb2;
    }
  }
}

// ---------------- fused projection GEMMs: one launch, 1280 blocks ----------------
// blocks [0,768):   A=qb, Bt=WtQcat (N=3072) -> Qbig scatter (seg = n>>10)
// blocks [768,1024): A=kb, Bt=WtK   (N=1024) -> Kbig seg 0
// blocks [1024,1280):A=vb, Bt=WtV   (N=1024) -> Vt [b][h][d][q] (packed q4 stores)
__global__ __launch_bounds__(256) void proj_gemm_kernel(
    const u16* __restrict__ qb, const u16* __restrict__ kb, const u16* __restrict__ vb,
    const u16* __restrict__ WtQcat, const u16* __restrict__ WtK, const u16* __restrict__ WtV,
    const float* __restrict__ bpq, const float* __restrict__ bhq, const float* __restrict__ bvq,
    const float* __restrict__ bk, const float* __restrict__ bv,
    u16* __restrict__ Qbig, u16* __restrict__ Kbig, u16* __restrict__ VtD) {
  __shared__ u16 lA[128 * 32];
  __shared__ u16 lB[128 * 32];
  int bid = blockIdx.x;
  const u16 *A, *Bt; const float* bias; u16* dst; int n0, m0, mode;
  if (bid < 768) {
    A = qb; Bt = WtQcat; dst = Qbig; mode = 0;
    n0 = (bid % 24) * 128; m0 = (bid / 24) * 128;
    const int seg = n0 >> 10;
    bias = seg == 0 ? bpq : (seg == 1 ? bhq : bvq);
  } else if (bid < 1024) {
    bid -= 768;
    A = kb; Bt = WtK; bias = bk; dst = Kbig; mode = 0;
    n0 = (bid % 8) * 128; m0 = (bid / 8) * 128;
  } else {
    bid -= 1024;
    A = vb; Bt = WtV; bias = bv; dst = VtD; mode = 1;
    n0 = (bid % 8) * 128; m0 = (bid / 8) * 128;
  }
  const int t = threadIdx.x;
  const int w = t >> 6, l = t & 63;
  const int wm = w >> 1, wn = w & 1;
  const int lr = l & 15, lg = l >> 4;
  f32x4 acc[4][4];
#pragma unroll
  for (int i = 0; i < 4; ++i)
#pragma unroll
    for (int j = 0; j < 4; ++j)
      acc[i][j] = (f32x4){0.f, 0.f, 0.f, 0.f};

  const int r0 = t >> 2, c0 = t & 3;

  for (int k0 = 0; k0 < 1024; k0 += 32) {
    gload_lds16(A + (size_t)(m0 + r0) * 1024 + k0 + c0 * 8, &lA[w * 512]);
    gload_lds16(A + (size_t)(m0 + 64 + r0) * 1024 + k0 + c0 * 8, &lA[2048 + w * 512]);
    gload_lds16(Bt + (size_t)(n0 + r0) * 1024 + k0 + c0 * 8, &lB[w * 512]);
    gload_lds16(Bt + (size_t)(n0 + 64 + r0) * 1024 + k0 + c0 * 8, &lB[2048 + w * 512]);
    __syncthreads();
    bf16x8 af[4], bfr[4];
#pragma unroll
    for (int i = 0; i < 4; ++i) {
      af[i]  = *(const bf16x8*)&lA[(wm * 64 + i * 16 + lr) * 32 + lg * 8];
      bfr[i] = *(const bf16x8*)&lB[(wn * 64 + i * 16 + lr) * 32 + lg * 8];
    }
#pragma unroll
    for (int i = 0; i < 4; ++i)
#pragma unroll
      for (int j = 0; j < 4; ++j)
        acc[i][j] = __builtin_amdgcn_mfma_f32_16x16x32_bf16(af[i], bfr[j], acc[i][j], 0, 0, 0);
    __syncthreads();
  }

#pragma unroll
  for (int i = 0; i < 4; ++i) {
    const int mb = m0 + wm * 64 + i * 16 + lg * 4;
    const int b = mb >> 10, qq = mb & 1023;
#pragma unroll
    for (int j = 0; j < 4; ++j) {
      const int n = n0 + wn * 64 + j * 16 + lr;
      const float bvv = bias[n & 1023];
      if (mode == 0) {
        const int seg = n >> 10, hh = (n & 1023) >> 6, d = n & 63;
        const size_t base = ((size_t)((b * H_ + hh) * L_ + qq)) * 192 + seg * 64 + d;
#pragma unroll
        for (int r = 0; r < 4; ++r)
          dst[base + (size_t)r * 192] = f2b(acc[i][j][r] + bvv);
      } else {
        const int hh = n >> 6, d = n & 63;
        ushort4 pk = make_ushort4(f2b(acc[i][j][0] + bvv), f2b(acc[i][j][1] + bvv),
                                  f2b(acc[i][j][2] + bvv), f2b(acc[i][j][3] + bvv));
        *(ushort4*)&dst[((size_t)((b * H_ + hh) * 64 + d)) * 1024 + qq] = pk;
      }
    }
  }
}

// ---------------- output GEMM: out[m][n] = ctx[m][k]*WtO[n][k] + bo[n], f32 out ----------------
__global__ __launch_bounds__(256) void out_gemm_kernel(
    const u16* __restrict__ A, const u16* __restrict__ Bt,
    const float* __restrict__ bias, float* __restrict__ dst) {
  __shared__ u16 lA[128 * 32];
  __shared__ u16 lB[128 * 32];
  const int t = threadIdx.x;
  const int w = t >> 6, l = t & 63;
  const int wm = w >> 1, wn = w & 1;
  const int lr = l & 15, lg = l >> 4;
  const int m0 = blockIdx.y * 128, n0 = blockIdx.x * 128;
  f32x4 acc[4][4];
#pragma unroll
  for (int i = 0; i < 4; ++i)
#pragma unroll
    for (int j = 0; j < 4; ++j)
      acc[i][j] = (f32x4){0.f, 0.f, 0.f, 0.f};
  const int r0 = t >> 2, c0 = t & 3;
  for (int k0 = 0; k0 < 1024; k0 += 32) {
    gload_lds16(A + (size_t)(m0 + r0) * 1024 + k0 + c0 * 8, &lA[w * 512]);
    gload_lds16(A + (size_t)(m0 + 64 + r0) * 1024 + k0 + c0 * 8, &lA[2048 + w * 512]);
    gload_lds16(Bt + (size_t)(n0 + r0) * 1024 + k0 + c0 * 8, &lB[w * 512]);
    gload_lds16(Bt + (size_t)(n0 + 64 + r0) * 1024 + k0 + c0 * 8, &lB[2048 + w * 512]);
    __syncthreads();
    bf16x8 af[4], bfr[4];
#pragma unroll
    for (int i = 0; i < 4; ++i) {
      af[i]  = *(const bf16x8*)&lA[(wm * 64 + i * 16 + lr) * 32 + lg * 8];
      bfr[i] = *(const bf16x8*)&lB[(wn * 64 + i * 16 + lr) * 32 + lg * 8];
    }
#pragma unroll
    for (int i = 0; i < 4; ++i)
#pragma unroll
      for (int j = 0; j < 4; ++j)
        acc[i][j] = __builtin_amdgcn_mfma_f32_16x16x32_bf16(af[i], bfr[j], acc[i][j], 0, 0, 0);
    __syncthreads();
  }
#pragma unroll
  for (int i = 0; i < 4; ++i) {
    const int mb = m0 + wm * 64 + i * 16 + lg * 4;
#pragma unroll
    for (int j = 0; j < 4; ++j) {
      const int n = n0 + wn * 64 + j * 16 + lr;
      const float bvv = bias[n];
#pragma unroll
      for (int r = 0; r < 4; ++r)
        dst[(size_t)(mb + r) * 1024 + n] = acc[i][j][r] + bvv;
    }
  }
}

// ---------------- attention: register-resident scores, swapped-operand QK^T ----------------
// block = (16 q-rows, h, b), 256 threads / 4 waves. Wave w owns kpos [w*256,(w+1)*256).
// mfma(K,Q) puts S^T in acc: lane owns q-row (col=lr), kpos = kp0 + lg*4 + r.
__global__ __launch_bounds__(256) void attn_kernel(
    const u16* __restrict__ Qbig, const u16* __restrict__ Kbig, const u16* __restrict__ Vt,
    float* __restrict__ attn_out, u16* __restrict__ ctx) {
  __shared__ u16 Plds[16][1032];   // P bf16, +8 pad breaks bank aliasing
  __shared__ float red[2][4][16];
  const int qt = blockIdx.x, h = blockIdx.y, b = blockIdx.z;
  const int bh = b * H_ + h;
  const int q0 = qt * 16;
  const int t = threadIdx.x, w = t >> 6, l = t & 63;
  const int lr = l & 15, lg = l >> 4;

  // Q B-fragment: col = q-row lr, k-chunk lg; 6 chunks of the 192-dim contraction
  bf16x8 aq[6];
  {
    const u16* Qrow = Qbig + ((size_t)bh * L_ + q0 + lr) * 192 + lg * 8;
#pragma unroll
    for (int c = 0; c < 6; ++c) aq[c] = *(const bf16x8*)(Qrow + c * 32);
  }

  const float scl = 1.0f / 24.0f;  // HD^-0.5 / 3
  float s[16][4];
#pragma unroll
  for (int kt = 0; kt < 16; ++kt) {
    const int kp0 = w * 256 + kt * 16;
    const u16* Krow = Kbig + ((size_t)bh * L_ + kp0 + lr) * 192 + lg * 8;
    f32x4 acc = (f32x4){0.f, 0.f, 0.f, 0.f};
#pragma unroll
    for (int c = 0; c < 6; ++c) {
      const bf16x8 kf = *(const bf16x8*)(Krow + c * 32);
      acc = __builtin_amdgcn_mfma_f32_16x16x32_bf16(kf, aq[c], acc, 0, 0, 0);
    }
#pragma unroll
    for (int r = 0; r < 4; ++r) s[kt][r] = acc[r] * scl;
  }

  // softmax over each lane's q-row (lr); lane covers kpos {w*256 + kt*16 + lg*4 + r}
  float mx = -1e30f;
#pragma unroll
  for (int kt = 0; kt < 16; ++kt)
#pragma unroll
    for (int r = 0; r < 4; ++r) mx = fmaxf(mx, s[kt][r]);
  mx = fmaxf(mx, __shfl_xor(mx, 16));
  mx = fmaxf(mx, __shfl_xor(mx, 32));
  if (lg == 0) red[0][w][lr] = mx;
  __syncthreads();
  mx = fmaxf(fmaxf(red[0][0][lr], red[0][1][lr]), fmaxf(red[0][2][lr], red[0][3][lr]));
  float sum = 0.f;
#pragma unroll
  for (int kt = 0; kt < 16; ++kt)
#pragma unroll
    for (int r = 0; r < 4; ++r) { s[kt][r] = __expf(s[kt][r] - mx); sum += s[kt][r]; }
  sum += __shfl_xor(sum, 16);
  sum += __shfl_xor(sum, 32);
  if (lg == 0) red[1][w][lr] = sum;
  __syncthreads();
  const float inv = 1.0f / (red[1][0][lr] + red[1][1][lr] + red[1][2][lr] + red[1][3][lr]);

  // normalized P: f32 -> HBM (float4), bf16 -> Plds (8B packed)
  float* aout = attn_out + ((size_t)bh * L_ + q0 + lr) * L_ + w * 256 + lg * 4;
#pragma unroll
  for (int kt = 0; kt < 16; ++kt) {
    const float p0 = s[kt][0] * inv, p1 = s[kt][1] * inv;
    const float p2 = s[kt][2] * inv, p3 = s[kt][3] * inv;
    *(float4*)(aout + kt * 16) = make_float4(p0, p1, p2, p3);
    *(ushort4*)&Plds[lr][w * 256 + kt * 16 + lg * 4] =
        make_ushort4(f2b(p0), f2b(p1), f2b(p2), f2b(p3));
  }
  __syncthreads();

  // PV: wave owns d-slice [w*16, w*16+16); A=P from LDS b128, B=V from global
  {
    const int dw = w * 16;
    const u16* Vrow = Vt + ((size_t)bh * 64 + dw + lr) * L_ + lg * 8;
    f32x4 acc = (f32x4){0.f, 0.f, 0.f, 0.f};
#pragma unroll
    for (int cc = 0; cc < 32; ++cc) {
      const bf16x8 pf = *(const bf16x8*)&Plds[lr][cc * 32 + lg * 8];
      const bf16x8 vf = *(const bf16x8*)(Vrow + cc * 32);
      acc = __builtin_amdgcn_mfma_f32_16x16x32_bf16(pf, vf, acc, 0, 0, 0);
    }
#pragma unroll
    for (int r = 0; r < 4; ++r)
      ctx[((size_t)(b * L_ + q0 + lg * 4 + r)) * D_ + h * 64 + dw + lr] = f2b(acc[r]);
  }
}

extern "C" void kernel_launch(void* const* d_in, const int* in_sizes, int n_in,
                              void* d_out, int out_size, void* d_ws, size_t ws_size,
                              hipStream_t stream) {
  (void)in_sizes; (void)n_in; (void)out_size; (void)ws_size;
  const float* q   = (const float*)d_in[0];
  const float* k   = (const float*)d_in[1];
  const float* v   = (const float*)d_in[2];
  const int* pitch = (const int*)d_in[3];
  const int* bass  = (const int*)d_in[4];
  const float* Wpq = (const float*)d_in[5];  const float* bpq  = (const float*)d_in[6];
  const float* Whq = (const float*)d_in[7];  const float* bhq  = (const float*)d_in[8];
  const float* Wvq = (const float*)d_in[9];  const float* bvq  = (const float*)d_in[10];
  const float* Wk  = (const float*)d_in[11]; const float* bk   = (const float*)d_in[12];
  const float* Wv  = (const float*)d_in[13]; const float* bv   = (const float*)d_in[14];
  const float* Wc  = (const float*)d_in[15]; const float* bc   = (const float*)d_in[16];
  const float* Wb  = (const float*)d_in[17]; const float* bbias= (const float*)d_in[18];
  const float* Wo  = (const float*)d_in[19]; const float* bo   = (const float*)d_in[20];

  char* ws = (char*)d_ws;
  const size_t MB = 1024 * 1024;
  u16* qb   = (u16*)(ws + 0 * MB);   // [4096][1024] bf16
  u16* kb   = (u16*)(ws + 8 * MB);
  u16* vb   = (u16*)(ws + 16 * MB);
  u16* WtPQ = (u16*)(ws + 24 * MB);  // [n][k] bf16; PQ|HQ|VQ contiguous = N=3072 concat
  u16* WtHQ = (u16*)(ws + 26 * MB);
  u16* WtVQ = (u16*)(ws + 28 * MB);
  u16* WtK  = (u16*)(ws + 30 * MB);
  u16* WtV  = (u16*)(ws + 32 * MB);
  u16* WtO  = (u16*)(ws + 34 * MB);
  u16* Qbig = (u16*)(ws + 36 * MB);  // [b][h][q][192] = pq|hq|vq
  u16* Kbig = (u16*)(ws + 60 * MB);  // [b][h][kpos][192] = k|cf|bf
  u16* Vt   = (u16*)(ws + 84 * MB);  // [b][h][d][kpos]
  u16* ctx  = (u16*)(ws + 92 * MB);  // [b*L][D] bf16

  float* out  = (float*)d_out;
  float* attn = out + (size_t)B_ * L_ * D_;

  cast3_kernel<<<dim3(4096), dim3(256), 0, stream>>>(
      (const float4*)q, (const float4*)k, (const float4*)v,
      (ushort4*)qb, (ushort4*)kb, (ushort4*)vb);
  twt_kernel<<<dim3(32, 32, 6), dim3(32, 8), 0, stream>>>(
      Wpq, Whq, Wvq, Wk, Wv, Wo, WtPQ, WtHQ, WtVQ, WtK, WtV, WtO);
  chordfeat_kernel<<<dim3(1024), dim3(256), 0, stream>>>(pitch, bass, Wc, bc, Wb, bbias, Kbig);
  proj_gemm_kernel<<<dim3(1280), dim3(256), 0, stream>>>(
      qb, kb, vb, WtPQ, WtK, WtV, bpq, bhq, bvq, bk, bv, Qbig, Kbig, Vt);
  attn_kernel<<<dim3(64, 16, 4), dim3(256), 0, stream>>>(Qbig, Kbig, Vt, attn, ctx);
  out_gemm_kernel<<<dim3(8, 32), dim3(256), 0, stream>>>(ctx, WtO, bo, out);
}

// Round 11
// 586.479 us; speedup vs baseline: 1.3162x; 1.2477x over previous
//
#include <hip/hip_runtime.h>

#define B_ 4
#define L_ 1024
#define D_ 1024
#define H_ 16

typedef unsigned short u16;
typedef __attribute__((ext_vector_type(8))) short bf16x8;
typedef __attribute__((ext_vector_type(4))) float f32x4;

__device__ __forceinline__ u16 f2b(float x) {
  union { float f; unsigned u; } v; v.f = x;
  unsigned r = v.u + 0x7FFFu + ((v.u >> 16) & 1u);
  return (u16)(r >> 16);
}

__device__ __forceinline__ void gload_lds16(const void* g, void* lds) {
  __builtin_amdgcn_global_load_lds((const __attribute__((address_space(1))) void*)g,
                                   (__attribute__((address_space(3))) void*)lds, 16, 0, 0);
}

// ---------------- cast query/key/value f32 -> bf16 ----------------
__global__ __launch_bounds__(256) void cast3_kernel(
    const float4* __restrict__ q, const float4* __restrict__ k, const float4* __restrict__ v,
    ushort4* __restrict__ qb, ushort4* __restrict__ kb, ushort4* __restrict__ vb) {
  int idx = blockIdx.x * 256 + threadIdx.x;
  float4 a = q[idx];
  qb[idx] = make_ushort4(f2b(a.x), f2b(a.y), f2b(a.z), f2b(a.w));
  a = k[idx];
  kb[idx] = make_ushort4(f2b(a.x), f2b(a.y), f2b(a.z), f2b(a.w));
  a = v[idx];
  vb[idx] = make_ushort4(f2b(a.x), f2b(a.y), f2b(a.z), f2b(a.w));
}

// ---------------- transpose + cast 6 weights: Wt[n][k] = W[k][n] ----------------
__global__ __launch_bounds__(256) void twt_kernel(
    const float* __restrict__ w0, const float* __restrict__ w1, const float* __restrict__ w2,
    const float* __restrict__ w3, const float* __restrict__ w4, const float* __restrict__ w5,
    u16* __restrict__ t0, u16* __restrict__ t1, u16* __restrict__ t2,
    u16* __restrict__ t3, u16* __restrict__ t4, u16* __restrict__ t5) {
  __shared__ float tile[32][33];
  const float* W; u16* T;
  switch (blockIdx.z) {
    case 0: W = w0; T = t0; break;
    case 1: W = w1; T = t1; break;
    case 2: W = w2; T = t2; break;
    case 3: W = w3; T = t3; break;
    case 4: W = w4; T = t4; break;
    default: W = w5; T = t5; break;
  }
  const int tx = threadIdx.x, ty = threadIdx.y;
  const int n0 = blockIdx.x * 32, k0 = blockIdx.y * 32;
#pragma unroll
  for (int jj = 0; jj < 4; ++jj)
    tile[ty + 8 * jj][tx] = W[(size_t)(k0 + ty + 8 * jj) * D_ + n0 + tx];
  __syncthreads();
#pragma unroll
  for (int jj = 0; jj < 4; ++jj)
    T[(size_t)(n0 + ty + 8 * jj) * D_ + k0 + tx] = f2b(tile[tx][ty + 8 * jj]);
}

// ---------------- chord / bass features -> Kbig segments 1,2 (all batches) ----------------
__global__ __launch_bounds__(256) void chordfeat_kernel(
    const int* __restrict__ pitch, const int* __restrict__ bass,
    const float* __restrict__ Wc, const float* __restrict__ bc,
    const float* __restrict__ Wb, const float* __restrict__ bbias,
    u16* __restrict__ Kbig) {
  const int ll = blockIdx.x, t = threadIdx.x;
  __shared__ float pc[12], bs[12];
  if (t < 12) { pc[t] = (float)pitch[ll * 12 + t]; bs[t] = (float)bass[ll * 12 + t]; }
  __syncthreads();
  for (int n = t; n < D_; n += 256) {
    float c = bc[n], vv = bbias[n];
#pragma unroll
    for (int j = 0; j < 12; ++j) { c += pc[j] * Wc[j * D_ + n]; vv += bs[j] * Wb[j * D_ + n]; }
    const u16 cb = f2b(c), vb2 = f2b(vv);
    const int hh = n >> 6, d = n & 63;
#pragma unroll
    for (int b = 0; b < B_; ++b) {
      const size_t base = ((size_t)((b * H_ + hh) * L_ + ll)) * 192;
      Kbig[base + 64 + d] = cb;
      Kbig[base + 128 + d] = vb2;
    }
  }
}

// ---------------- fused projection GEMMs: one launch, 1280 blocks ----------------
__global__ __launch_bounds__(256) void proj_gemm_kernel(
    const u16* __restrict__ qb, const u16* __restrict__ kb, const u16* __restrict__ vb,
    const u16* __restrict__ WtQcat, const u16* __restrict__ WtK, const u16* __restrict__ WtV,
    const float* __restrict__ bpq, const float* __restrict__ bhq, const float* __restrict__ bvq,
    const float* __restrict__ bk, const float* __restrict__ bv,
    u16* __restrict__ Qbig, u16* __restrict__ Kbig, u16* __restrict__ VtD) {
  __shared__ u16 lA[128 * 32];
  __shared__ u16 lB[128 * 32];
  int bid = blockIdx.x;
  const u16 *A, *Bt; const float* bias; u16* dst; int n0, m0, mode;
  if (bid < 768) {
    A = qb; Bt = WtQcat; dst = Qbig; mode = 0;
    n0 = (bid % 24) * 128; m0 = (bid / 24) * 128;
    const int seg = n0 >> 10;
    bias = seg == 0 ? bpq : (seg == 1 ? bhq : bvq);
  } else if (bid < 1024) {
    bid -= 768;
    A = kb; Bt = WtK; bias = bk; dst = Kbig; mode = 0;
    n0 = (bid % 8) * 128; m0 = (bid / 8) * 128;
  } else {
    bid -= 1024;
    A = vb; Bt = WtV; bias = bv; dst = VtD; mode = 1;
    n0 = (bid % 8) * 128; m0 = (bid / 8) * 128;
  }
  const int t = threadIdx.x;
  const int w = t >> 6, l = t & 63;
  const int wm = w >> 1, wn = w & 1;
  const int lr = l & 15, lg = l >> 4;
  f32x4 acc[4][4];
#pragma unroll
  for (int i = 0; i < 4; ++i)
#pragma unroll
    for (int j = 0; j < 4; ++j)
      acc[i][j] = (f32x4){0.f, 0.f, 0.f, 0.f};

  const int r0 = t >> 2, c0 = t & 3;

  for (int k0 = 0; k0 < 1024; k0 += 32) {
    gload_lds16(A + (size_t)(m0 + r0) * 1024 + k0 + c0 * 8, &lA[w * 512]);
    gload_lds16(A + (size_t)(m0 + 64 + r0) * 1024 + k0 + c0 * 8, &lA[2048 + w * 512]);
    gload_lds16(Bt + (size_t)(n0 + r0) * 1024 + k0 + c0 * 8, &lB[w * 512]);
    gload_lds16(Bt + (size_t)(n0 + 64 + r0) * 1024 + k0 + c0 * 8, &lB[2048 + w * 512]);
    __syncthreads();
    bf16x8 af[4], bfr[4];
#pragma unroll
    for (int i = 0; i < 4; ++i) {
      af[i]  = *(const bf16x8*)&lA[(wm * 64 + i * 16 + lr) * 32 + lg * 8];
      bfr[i] = *(const bf16x8*)&lB[(wn * 64 + i * 16 + lr) * 32 + lg * 8];
    }
#pragma unroll
    for (int i = 0; i < 4; ++i)
#pragma unroll
      for (int j = 0; j < 4; ++j)
        acc[i][j] = __builtin_amdgcn_mfma_f32_16x16x32_bf16(af[i], bfr[j], acc[i][j], 0, 0, 0);
    __syncthreads();
  }

#pragma unroll
  for (int i = 0; i < 4; ++i) {
    const int mb = m0 + wm * 64 + i * 16 + lg * 4;
    const int b = mb >> 10, qq = mb & 1023;
#pragma unroll
    for (int j = 0; j < 4; ++j) {
      const int n = n0 + wn * 64 + j * 16 + lr;
      const float bvv = bias[n & 1023];
      if (mode == 0) {
        const int seg = n >> 10, hh = (n & 1023) >> 6, d = n & 63;
        const size_t base = ((size_t)((b * H_ + hh) * L_ + qq)) * 192 + seg * 64 + d;
#pragma unroll
        for (int r = 0; r < 4; ++r)
          dst[base + (size_t)r * 192] = f2b(acc[i][j][r] + bvv);
      } else {
        const int hh = n >> 6, d = n & 63;
        ushort4 pk = make_ushort4(f2b(acc[i][j][0] + bvv), f2b(acc[i][j][1] + bvv),
                                  f2b(acc[i][j][2] + bvv), f2b(acc[i][j][3] + bvv));
        *(ushort4*)&dst[((size_t)((b * H_ + hh) * 64 + d)) * 1024 + qq] = pk;
      }
    }
  }
}

// ---------------- output GEMM: out[m][n] = ctx[m][k]*WtO[n][k] + bo[n], f32 out ----------------
__global__ __launch_bounds__(256) void out_gemm_kernel(
    const u16* __restrict__ A, const u16* __restrict__ Bt,
    const float* __restrict__ bias, float* __restrict__ dst) {
  __shared__ u16 lA[128 * 32];
  __shared__ u16 lB[128 * 32];
  const int t = threadIdx.x;
  const int w = t >> 6, l = t & 63;
  const int wm = w >> 1, wn = w & 1;
  const int lr = l & 15, lg = l >> 4;
  const int m0 = blockIdx.y * 128, n0 = blockIdx.x * 128;
  f32x4 acc[4][4];
#pragma unroll
  for (int i = 0; i < 4; ++i)
#pragma unroll
    for (int j = 0; j < 4; ++j)
      acc[i][j] = (f32x4){0.f, 0.f, 0.f, 0.f};
  const int r0 = t >> 2, c0 = t & 3;
  for (int k0 = 0; k0 < 1024; k0 += 32) {
    gload_lds16(A + (size_t)(m0 + r0) * 1024 + k0 + c0 * 8, &lA[w * 512]);
    gload_lds16(A + (size_t)(m0 + 64 + r0) * 1024 + k0 + c0 * 8, &lA[2048 + w * 512]);
    gload_lds16(Bt + (size_t)(n0 + r0) * 1024 + k0 + c0 * 8, &lB[w * 512]);
    gload_lds16(Bt + (size_t)(n0 + 64 + r0) * 1024 + k0 + c0 * 8, &lB[2048 + w * 512]);
    __syncthreads();
    bf16x8 af[4], bfr[4];
#pragma unroll
    for (int i = 0; i < 4; ++i) {
      af[i]  = *(const bf16x8*)&lA[(wm * 64 + i * 16 + lr) * 32 + lg * 8];
      bfr[i] = *(const bf16x8*)&lB[(wn * 64 + i * 16 + lr) * 32 + lg * 8];
    }
#pragma unroll
    for (int i = 0; i < 4; ++i)
#pragma unroll
      for (int j = 0; j < 4; ++j)
        acc[i][j] = __builtin_amdgcn_mfma_f32_16x16x32_bf16(af[i], bfr[j], acc[i][j], 0, 0, 0);
    __syncthreads();
  }
#pragma unroll
  for (int i = 0; i < 4; ++i) {
    const int mb = m0 + wm * 64 + i * 16 + lg * 4;
#pragma unroll
    for (int j = 0; j < 4; ++j) {
      const int n = n0 + wn * 64 + j * 16 + lr;
      const float bvv = bias[n];
#pragma unroll
      for (int r = 0; r < 4; ++r)
        dst[(size_t)(mb + r) * 1024 + n] = acc[i][j][r] + bvv;
    }
  }
}

// ---------------- attention v3: flash-style, LDS-staged K/V shared by 4 waves ----------------
// block = 64 q-rows (4 waves x 16 q), grid (16,16,4). KT=32 kpos per tile, 32 tiles.
// Pass 1: online (m,l) per q-row (wave-private, no softmax barriers).
// Pass 2: recompute scores, write normalized attn (float4), pack P bf16 -> wave-private LDS,
//         accumulate PV from LDS-staged V tiles.
// K tile LDS is XOR-swizzled (m214 fix: row stride 384B == 0 mod 128) via pre-swizzled
// global source (glds dest must stay linear) + swizzled ds_read.
__global__ __launch_bounds__(256) void attn_kernel(
    const u16* __restrict__ Qbig, const u16* __restrict__ Kbig, const u16* __restrict__ Vt,
    float* __restrict__ attn_out, u16* __restrict__ ctx) {
  __shared__ u16 Kl[2][32 * 192];   // 24 KiB, swizzled: u16 idx ^= ((row&7)<<3)
  __shared__ u16 Vl[2][64 * 32];    // 8 KiB, linear [d][k]
  __shared__ u16 Pl[4][16 * 40];    // 5 KiB, per-wave P tile, row stride 40 (16B-aligned rows)
  const int qt = blockIdx.x, h = blockIdx.y, b = blockIdx.z;
  const int bh = b * H_ + h;
  const int q0 = qt * 64;
  const int t = threadIdx.x, wq = t >> 6, l = t & 63;
  const int lr = l & 15, lg = l >> 4;

  // Q fragments: this wave's 16 q-rows, 6 k-chunks of the 192-dim contraction
  bf16x8 aq[6];
  {
    const u16* Qrow = Qbig + ((size_t)bh * L_ + q0 + wq * 16 + lr) * 192 + lg * 8;
#pragma unroll
    for (int c = 0; c < 6; ++c) aq[c] = *(const bf16x8*)(Qrow + c * 32);
  }

  const u16* Kbase = Kbig + (size_t)bh * L_ * 192;
  const u16* Vbase = Vt + (size_t)bh * 64 * L_;

  // per-thread K staging source offsets (u16, tile-relative), pre-swizzled:
  // dest byte off = chunk*1024 + lane*16; row = off/384; src col = col ^ ((row&7)<<4)
  int ksrc[3];
#pragma unroll
  for (int i = 0; i < 3; ++i) {
    const int off = (wq * 3 + i) * 1024 + l * 16;
    const int row = off / 384;
    const int col = off - row * 384;
    ksrc[i] = row * 192 + (((col ^ ((row & 7) << 4))) >> 1);
  }
  // V staging: dest byte off = wq*1024 + lane*16 -> d = off/64, col u16 = (off%64)/2
  const int voff = wq * 1024 + l * 16;
  const int vd = voff >> 6, vcol = (voff & 63) >> 1;

  const float scl = 1.0f / 24.0f;  // HD^-0.5 / 3
  float m = -1e30f, lden = 0.f;

  // swizzled read column (shared by both 16-row subtiles: (sub*16+lr)&7 == lr&7)
  int csw[6];
#pragma unroll
  for (int c = 0; c < 6; ++c) csw[c] = (c * 32 + lg * 8) ^ ((lr & 7) << 3);

  // ---- pass 1: online max & denom ----
#pragma unroll
  for (int i = 0; i < 3; ++i)
    gload_lds16(Kbase + ksrc[i], &Kl[0][(wq * 3 + i) * 512]);
  __syncthreads();

  for (int ti = 0; ti < 32; ++ti) {
    const int cur = ti & 1;
    if (ti < 31) {
#pragma unroll
      for (int i = 0; i < 3; ++i)
        gload_lds16(Kbase + (size_t)(ti + 1) * 32 * 192 + ksrc[i],
                    &Kl[cur ^ 1][(wq * 3 + i) * 512]);
    }
    f32x4 a0 = (f32x4){0.f, 0.f, 0.f, 0.f}, a1 = (f32x4){0.f, 0.f, 0.f, 0.f};
#pragma unroll
    for (int c = 0; c < 6; ++c) {
      const bf16x8 k0 = *(const bf16x8*)&Kl[cur][lr * 192 + csw[c]];
      const bf16x8 k1 = *(const bf16x8*)&Kl[cur][(16 + lr) * 192 + csw[c]];
      a0 = __builtin_amdgcn_mfma_f32_16x16x32_bf16(k0, aq[c], a0, 0, 0, 0);
      a1 = __builtin_amdgcn_mfma_f32_16x16x32_bf16(k1, aq[c], a1, 0, 0, 0);
    }
    float tm = fmaxf(fmaxf(fmaxf(a0[0], a0[1]), fmaxf(a0[2], a0[3])),
                     fmaxf(fmaxf(a1[0], a1[1]), fmaxf(a1[2], a1[3]))) * scl;
    tm = fmaxf(tm, __shfl_xor(tm, 16));
    tm = fmaxf(tm, __shfl_xor(tm, 32));
    const float mn = fmaxf(m, tm);
    float ps = __expf(a0[0] * scl - mn) + __expf(a0[1] * scl - mn) +
               __expf(a0[2] * scl - mn) + __expf(a0[3] * scl - mn) +
               __expf(a1[0] * scl - mn) + __expf(a1[1] * scl - mn) +
               __expf(a1[2] * scl - mn) + __expf(a1[3] * scl - mn);
    ps += __shfl_xor(ps, 16);
    ps += __shfl_xor(ps, 32);
    lden = lden * __expf(m - mn) + ps;
    m = mn;
    __syncthreads();
  }

  const float invl = 1.0f / lden;

  // ---- pass 2: recompute, write attn, PV ----
#pragma unroll
  for (int i = 0; i < 3; ++i)
    gload_lds16(Kbase + ksrc[i], &Kl[0][(wq * 3 + i) * 512]);
  gload_lds16(Vbase + (size_t)vd * L_ + vcol, &Vl[0][wq * 512]);
  __syncthreads();

  f32x4 opv[4];
#pragma unroll
  for (int dc = 0; dc < 4; ++dc) opv[dc] = (f32x4){0.f, 0.f, 0.f, 0.f};
  u16* Pw = &Pl[wq][0];
  float* arow = attn_out + ((size_t)bh * L_ + q0 + wq * 16 + lr) * L_;

  for (int ti = 0; ti < 32; ++ti) {
    const int cur = ti & 1;
    if (ti < 31) {
#pragma unroll
      for (int i = 0; i < 3; ++i)
        gload_lds16(Kbase + (size_t)(ti + 1) * 32 * 192 + ksrc[i],
                    &Kl[cur ^ 1][(wq * 3 + i) * 512]);
      gload_lds16(Vbase + (size_t)vd * L_ + (ti + 1) * 32 + vcol, &Vl[cur ^ 1][wq * 512]);
    }
    f32x4 a0 = (f32x4){0.f, 0.f, 0.f, 0.f}, a1 = (f32x4){0.f, 0.f, 0.f, 0.f};
#pragma unroll
    for (int c = 0; c < 6; ++c) {
      const bf16x8 k0 = *(const bf16x8*)&Kl[cur][lr * 192 + csw[c]];
      const bf16x8 k1 = *(const bf16x8*)&Kl[cur][(16 + lr) * 192 + csw[c]];
      a0 = __builtin_amdgcn_mfma_f32_16x16x32_bf16(k0, aq[c], a0, 0, 0, 0);
      a1 = __builtin_amdgcn_mfma_f32_16x16x32_bf16(k1, aq[c], a1, 0, 0, 0);
    }
    const float p0 = __expf(a0[0] * scl - m) * invl, p1 = __expf(a0[1] * scl - m) * invl;
    const float p2 = __expf(a0[2] * scl - m) * invl, p3 = __expf(a0[3] * scl - m) * invl;
    const float p4 = __expf(a1[0] * scl - m) * invl, p5 = __expf(a1[1] * scl - m) * invl;
    const float p6 = __expf(a1[2] * scl - m) * invl, p7 = __expf(a1[3] * scl - m) * invl;
    *(float4*)(arow + ti * 32 + lg * 4) = make_float4(p0, p1, p2, p3);
    *(float4*)(arow + ti * 32 + 16 + lg * 4) = make_float4(p4, p5, p6, p7);
    *(ushort4*)&Pw[lr * 40 + lg * 4] = make_ushort4(f2b(p0), f2b(p1), f2b(p2), f2b(p3));
    *(ushort4*)&Pw[lr * 40 + 16 + lg * 4] = make_ushort4(f2b(p4), f2b(p5), f2b(p6), f2b(p7));
    const bf16x8 pf = *(const bf16x8*)&Pw[lr * 40 + lg * 8];
#pragma unroll
    for (int dc = 0; dc < 4; ++dc) {
      const bf16x8 vf = *(const bf16x8*)&Vl[cur][(dc * 16 + lr) * 32 + lg * 8];
      opv[dc] = __builtin_amdgcn_mfma_f32_16x16x32_bf16(pf, vf, opv[dc], 0, 0, 0);
    }
    __syncthreads();
  }

#pragma unroll
  for (int dc = 0; dc < 4; ++dc)
#pragma unroll
    for (int r = 0; r < 4; ++r)
      ctx[((size_t)(b * L_ + q0 + wq * 16 + lg * 4 + r)) * D_ + h * 64 + dc * 16 + lr] =
          f2b(opv[dc][r]);
}

extern "C" void kernel_launch(void* const* d_in, const int* in_sizes, int n_in,
                              void* d_out, int out_size, void* d_ws, size_t ws_size,
                              hipStream_t stream) {
  (void)in_sizes; (void)n_in; (void)out_size; (void)ws_size;
  const float* q   = (const float*)d_in[0];
  const float* k   = (const float*)d_in[1];
  const float* v   = (const float*)d_in[2];
  const int* pitch = (const int*)d_in[3];
  const int* bass  = (const int*)d_in[4];
  const float* Wpq = (const float*)d_in[5];  const float* bpq  = (const float*)d_in[6];
  const float* Whq = (const float*)d_in[7];  const float* bhq  = (const float*)d_in[8];
  const float* Wvq = (const float*)d_in[9];  const float* bvq  = (const float*)d_in[10];
  const float* Wk  = (const float*)d_in[11]; const float* bk   = (const float*)d_in[12];
  const float* Wv  = (const float*)d_in[13]; const float* bv   = (const float*)d_in[14];
  const float* Wc  = (const float*)d_in[15]; const float* bc   = (const float*)d_in[16];
  const float* Wb  = (const float*)d_in[17]; const float* bbias= (const float*)d_in[18];
  const float* Wo  = (const float*)d_in[19]; const float* bo   = (const float*)d_in[20];

  char* ws = (char*)d_ws;
  const size_t MB = 1024 * 1024;
  u16* qb   = (u16*)(ws + 0 * MB);   // [4096][1024] bf16
  u16* kb   = (u16*)(ws + 8 * MB);
  u16* vb   = (u16*)(ws + 16 * MB);
  u16* WtPQ = (u16*)(ws + 24 * MB);  // [n][k] bf16; PQ|HQ|VQ contiguous = N=3072 concat
  u16* WtHQ = (u16*)(ws + 26 * MB);
  u16* WtVQ = (u16*)(ws + 28 * MB);
  u16* WtK  = (u16*)(ws + 30 * MB);
  u16* WtV  = (u16*)(ws + 32 * MB);
  u16* WtO  = (u16*)(ws + 34 * MB);
  u16* Qbig = (u16*)(ws + 36 * MB);  // [b][h][q][192] = pq|hq|vq
  u16* Kbig = (u16*)(ws + 60 * MB);  // [b][h][kpos][192] = k|cf|bf
  u16* Vt   = (u16*)(ws + 84 * MB);  // [b][h][d][kpos]
  u16* ctx  = (u16*)(ws + 92 * MB);  // [b*L][D] bf16

  float* out  = (float*)d_out;
  float* attn = out + (size_t)B_ * L_ * D_;

  cast3_kernel<<<dim3(4096), dim3(256), 0, stream>>>(
      (const float4*)q, (const float4*)k, (const float4*)v,
      (ushort4*)qb, (ushort4*)kb, (ushort4*)vb);
  twt_kernel<<<dim3(32, 32, 6), dim3(32, 8), 0, stream>>>(
      Wpq, Whq, Wvq, Wk, Wv, Wo, WtPQ, WtHQ, WtVQ, WtK, WtV, WtO);
  chordfeat_kernel<<<dim3(1024), dim3(256), 0, stream>>>(pitch, bass, Wc, bc, Wb, bbias, Kbig);
  proj_gemm_kernel<<<dim3(1280), dim3(256), 0, stream>>>(
      qb, kb, vb, WtPQ, WtK, WtV, bpq, bhq, bvq, bk, bv, Qbig, Kbig, Vt);
  attn_kernel<<<dim3(16, 16, 4), dim3(256), 0, stream>>>(Qbig, Kbig, Vt, attn, ctx);
  out_gemm_kernel<<<dim3(8, 32), dim3(256), 0, stream>>>(ctx, WtO, bo, out);
}